// Round 10
// baseline (1511.244 us; speedup 1.0000x reference)
//
#include <hip/hip_runtime.h>
#include <hip/hip_fp8.h>

typedef unsigned short u16;
typedef unsigned char u8;
typedef __attribute__((ext_vector_type(8))) __bf16 bfrag;
typedef long long f8frag;
typedef __attribute__((ext_vector_type(4))) float f32x4;

static __device__ __forceinline__ f32x4 MFMA(bfrag a, bfrag b, f32x4 c) {
  return __builtin_amdgcn_mfma_f32_16x16x32_bf16(a, b, c, 0, 0, 0);
}
static __device__ __forceinline__ f32x4 MFMA8(f8frag a, f8frag b, f32x4 c) {
  return __builtin_amdgcn_mfma_f32_16x16x32_fp8_fp8(a, b, c, 0, 0, 0);
}

// float -> bf16 (RNE)
static __device__ __forceinline__ u16 f2b(float f) {
  union { float f; unsigned u; } v; v.f = f;
  unsigned r = (v.u + 0x7fffu + ((v.u >> 16) & 1u)) >> 16;
  return (u16)r;
}
// float -> fp8 e4m3 (OCP)
static __device__ __forceinline__ u8 f2e4m3(float f) {
  return __hip_fp8_e4m3(f).__x;
}
static __device__ __forceinline__ float ssig(float x) { return 1.f / (1.f + __expf(-x)); }
static __device__ __forceinline__ float stanh(float x) { return 1.f - 2.f / (__expf(2.f * x) + 1.f); }

// ---------------------------------------------------------------------------
// prep. Decode gate-retile: MFMA col n = g16*64 + gate*16 + m15 <-> source
// row gate*256 + g16*16 + m15 (g16 = hcol group 0..15).
// Cases 16/17: g-/o-gate fp8 lane-swizzled for LDS staging:
//   W[( (g16*8+kt)*64 + lane )*8 + j] = gate[hcol=g16*16+(lane&15)][k=kt*32+(lane>>4)*8+j]
// Pred (fp8): n' = hcol*4 + gate.
// ---------------------------------------------------------------------------
struct PrepArgs {
  const float *x, *W1, *W2, *W3, *Wh1, *Wc1, *Wx1, *Wh2, *Wc2, *Wx2;
  const float *rWih, *rWhh, *rbih, *rbhh, *pWih, *pWhh, *pbih, *pbhh;
  u16 *Xbf, *W1b, *W2b, *W3b, *Wh1b, *Wc1b, *Wx1b, *Wh2b, *Wc2b, *Wx2b;
  u16 *WcatR;
  u8 *Wc8, *Wg8, *Wo8, *pW8, *pWhh8;
  float *rbR, *pbR;
};

__global__ __launch_bounds__(256) void prep(PrepArgs p) {
  const int tid0 = blockIdx.x * 256 + threadIdx.x;
  const int stride = gridDim.x * 256;
  switch (blockIdx.y) {
    case 0: for (int i = tid0; i < 131072; i += stride) p.Xbf[i] = f2b(p.x[i]); break;
    case 1: for (int i = tid0; i < 65536;  i += stride) p.W1b[i] = f2b(p.W1[i]); break;
    case 2: for (int i = tid0; i < 262144; i += stride) p.W2b[i] = f2b(p.W2[i]); break;
    case 3: for (int i = tid0; i < 262144; i += stride) p.W3b[i] = f2b(p.W3[i]); break;
    case 4: for (int i = tid0; i < 262144; i += stride) p.Wh1b[i] = f2b(p.Wh1[i]); break;
    case 5: for (int i = tid0; i < 262144; i += stride) p.Wc1b[i] = f2b(p.Wc1[i]); break;
    case 6: for (int i = tid0; i < 262144; i += stride) p.Wx1b[i] = f2b(p.Wx1[i]); break;
    case 7: for (int i = tid0; i < 131072; i += stride) p.Wh2b[i] = f2b(p.Wh2[i]); break;
    case 8: for (int i = tid0; i < 131072; i += stride) p.Wc2b[i] = f2b(p.Wc2[i]); break;
    case 9: for (int i = tid0; i < 131072; i += stride) p.Wx2b[i] = f2b(p.Wx2[i]); break;
    case 10: // step-0 concat weights (bf16, gate-retiled)
      for (int i = tid0; i < 262144; i += stride) {
        int n = i >> 8, k = i & 255;
        int srow = (((n >> 4) & 3) << 8) + ((n >> 6) << 4) + (n & 15);
        p.WcatR[n * 512 + k] = f2b(p.rWih[srow * 256 + k]);
        p.WcatR[n * 512 + 256 + k] = f2b(p.rWhh[srow * 256 + k]);
      }
      break;
    case 11:
      for (int i = tid0; i < 1024; i += stride) {
        int srow = (((i >> 4) & 3) << 8) + ((i >> 6) << 4) + (i & 15);
        p.rbR[i] = p.rbih[srow] + p.rbhh[srow];
      }
      break;
    case 12: // pred x-weights fp8, gate-reordered
      for (int i = tid0; i < 32768; i += stride) {
        int n2 = i >> 8, k = i & 255;
        int srow = ((n2 & 3) << 5) + (n2 >> 2);
        p.pW8[i] = f2e4m3(p.pWih[srow * 256 + k]);
      }
      break;
    case 13: // pred h-weights fp8
      for (int i = tid0; i < 4096; i += stride) {
        int n2 = i >> 5, k = i & 31;
        int srow = ((n2 & 3) << 5) + (n2 >> 2);
        p.pWhh8[i] = f2e4m3(p.pWhh[srow * 32 + k]);
      }
      break;
    case 14:
      for (int i = tid0; i < 128; i += stride) {
        int srow = ((i & 3) << 5) + (i >> 2);
        p.pbR[i] = p.pbih[srow] + p.pbhh[srow];
      }
      break;
    case 15: // combined decode weights fp8, gate-retiled (streamed i,f)
      for (int i = tid0; i < 262144; i += stride) {
        int n = i >> 8, k = i & 255;
        int srow = (((n >> 4) & 3) << 8) + ((n >> 6) << 4) + (n & 15);
        p.Wc8[i] = f2e4m3(p.rWih[srow * 256 + k] + p.rWhh[srow * 256 + k]);
      }
      break;
    case 16: // g-gate fp8, lane-swizzled for LDS staging
      for (int i = tid0; i < 65536; i += stride) {
        int j = i & 7, lane = (i >> 3) & 63, kt = (i >> 9) & 7, g16 = i >> 12;
        int srow = 512 + g16 * 16 + (lane & 15);
        int k = kt * 32 + (lane >> 4) * 8 + j;
        p.Wg8[i] = f2e4m3(p.rWih[srow * 256 + k] + p.rWhh[srow * 256 + k]);
      }
      break;
    case 17: // o-gate fp8, lane-swizzled for LDS staging
      for (int i = tid0; i < 65536; i += stride) {
        int j = i & 7, lane = (i >> 3) & 63, kt = (i >> 9) & 7, g16 = i >> 12;
        int srow = 768 + g16 * 16 + (lane & 15);
        int k = kt * 32 + (lane >> 4) * 8 + j;
        p.Wo8[i] = f2e4m3(p.rWih[srow * 256 + k] + p.rWhh[srow * 256 + k]);
      }
      break;
  }
}

// ---------------------------------------------------------------------------
// gemm_act: Y[1024,N] = act(X[1024,K] @ W[N,K]^T + bias), bf16 in, fp32 acc.
// ---------------------------------------------------------------------------
__global__ __launch_bounds__(256) void gemm_act(
    const u16* __restrict__ X, const u16* __restrict__ W,
    const float* __restrict__ bias,
    u16* __restrict__ Yb, float* __restrict__ Yf,
    int K, int ldo, int coloff, int leaky) {
  const int rt = blockIdx.x, ct = blockIdx.y;
  const int lane = threadIdx.x & 63, wave = threadIdx.x >> 6;
  const int m15 = lane & 15, q = lane >> 4, kq = q * 8;
  const int row = rt * 64 + wave * 16 + m15;
  f32x4 acc[4] = {};
  const u16* xp = X + (size_t)row * K + kq;
  for (int k0 = 0; k0 < K; k0 += 32) {
    bfrag a = *(const bfrag*)(xp + k0);
#pragma unroll
    for (int nt = 0; nt < 4; nt++) {
      const u16* wp = W + (size_t)(ct * 64 + nt * 16 + m15) * K + k0 + kq;
      acc[nt] = MFMA(a, *(const bfrag*)wp, acc[nt]);
    }
  }
#pragma unroll
  for (int nt = 0; nt < 4; nt++) {
    int col = ct * 64 + nt * 16 + m15;
    float bv = bias[col];
#pragma unroll
    for (int r = 0; r < 4; r++) {
      int orow = rt * 64 + wave * 16 + q * 4 + r;
      float v = acc[nt][r] + bv;
      if (leaky) v = v >= 0.f ? v : 0.2f * v;
      if (Yb) Yb[(size_t)orow * ldo + coloff + col] = f2b(v);
      else    Yf[(size_t)orow * ldo + coloff + col] = v;
    }
  }
}

// ---------------------------------------------------------------------------
// decode_step: step 0 only (K=512 concat input, bf16), gate-retiled columns.
// ---------------------------------------------------------------------------
__global__ __launch_bounds__(256) void decode_step(
    const u16* __restrict__ A, const u16* __restrict__ W,
    const float* __restrict__ rb,
    float* __restrict__ C, u16* __restrict__ Hout, int K) {
  __shared__ float g[64][128];
  const int rt = blockIdx.x, cg = blockIdx.y;
  const int lane = threadIdx.x & 63, wave = threadIdx.x >> 6;
  const int m15 = lane & 15, q = lane >> 4, kq = q * 8;
  const int row = rt * 64 + wave * 16 + m15;
  f32x4 acc[8] = {};
  const u16* ap = A + (size_t)row * K + kq;
  for (int k0 = 0; k0 < K; k0 += 32) {
    bfrag a = *(const bfrag*)(ap + k0);
#pragma unroll
    for (int nt = 0; nt < 8; nt++) {
      const u16* wp = W + (size_t)(cg * 128 + nt * 16 + m15) * K + k0 + kq;
      acc[nt] = MFMA(a, *(const bfrag*)wp, acc[nt]);
    }
  }
#pragma unroll
  for (int nt = 0; nt < 8; nt++)
#pragma unroll
    for (int r = 0; r < 4; r++)
      g[wave * 16 + q * 4 + r][nt * 16 + m15] = acc[nt][r];
  __syncthreads();
  for (int t = threadIdx.x; t < 2048; t += 256) {
    int rl = t >> 5, hc = t & 31;
    int grow = rt * 64 + rl, gcol = cg * 32 + hc;
    int base = ((hc >> 4) << 6) + (hc & 15);
    float gi = g[rl][base +  0] + rb[cg * 128 + base +  0];
    float gf = g[rl][base + 16] + rb[cg * 128 + base + 16];
    float gg = g[rl][base + 32] + rb[cg * 128 + base + 32];
    float go = g[rl][base + 48] + rb[cg * 128 + base + 48];
    size_t ci = (size_t)grow * 256 + gcol;
    float c = C[ci];
    float cn = ssig(gf) * c + ssig(gi) * stanh(gg);
    float hn = ssig(go) * stanh(cn);
    C[ci] = cn;
    Hout[ci] = f2b(hn);
  }
}

// ---------------------------------------------------------------------------
// decode_pred v5 (wave-specialized): 64 blocks x 1024 thr, 16 rows/block.
// R3..R9 invariant: ~20-22K cyc/step regardless of bytes/placement, pipes
// <10% busy -> latency serialization (3 barriers/step lockstep + pred serial
// after decode). Restructure:
//   waves 8..15 = DECODE crew: step s+1 (each wave 2 col-groups = 64 MFMAs,
//                 8 indep chains). g,o weights from LDS fp8; i,f streamed fp8.
//   waves 0..7  = PRED crew: stats+out for step s-1 (register-only shuffle
//                 softmax), then pred MFMAs for step s. All fp8.
// ONE barrier per step; decode(s+1) runs concurrently with pred(s).
// ---------------------------------------------------------------------------
__global__ __launch_bounds__(1024, 4) void decode_pred(
    const u8* __restrict__ Wc8,     // [1024][256] fp8 gate-retiled (i,f)
    const u8* __restrict__ Wg8,     // [65536] swizzled fp8 g-gate
    const u8* __restrict__ Wo8,     // [65536] swizzled fp8 o-gate
    const float* __restrict__ rb,   // rbR [1024]
    const float* __restrict__ C0,   // CB  [1024][256] (c after step 0)
    const u16* __restrict__ H0,     // h_0 [1024][256] bf16
    const u8* __restrict__ pW8,     // [128][256] fp8
    const u8* __restrict__ pWhh8,   // [128][32] fp8
    const float* __restrict__ pb,   // pbR [128]
    float* __restrict__ out) {      // [1024][128][32]
  __shared__ u8 wgl8[16][8][512];      // 64 KB g-gate
  __shared__ u8 wol8[16][8][512];      // 64 KB o-gate
  __shared__ u8 hbuf8[2][16][272];     // 8.5 KB fp8 h
  __shared__ float gbuf[8][16][20];    // 10 KB pred transpose
  __shared__ u8 hp8[2][16][40];        // 1.25 KB pred hidden (fp8)
  __shared__ float ys[2][16][36];      // 4.5 KB pred y (double-buffered)
  const int tid = threadIdx.x;
  const int w = tid >> 6, lane = tid & 63;
  const int m15 = lane & 15, q = lane >> 4;
  const int rowg = blockIdx.x * 16;

  // stage g/o fp8 weights (one-time, layout == read order)
  for (int i = tid * 8; i < 65536; i += 8192) {
    *(unsigned long long*)(&wgl8[0][0][0] + i) = *(const unsigned long long*)(Wg8 + i);
    *(unsigned long long*)(&wol8[0][0][0] + i) = *(const unsigned long long*)(Wo8 + i);
  }
  // h_0 -> fp8
  {
    int r = tid >> 6, c = (tid & 63) * 4;
    const u16* src = H0 + (size_t)(rowg + r) * 256 + c;
    u8 b4[4];
#pragma unroll
    for (int j = 0; j < 4; j++) {
      union { float f; unsigned u; } v; v.u = (unsigned)src[j] << 16;
      b4[j] = f2e4m3(v.f);
    }
    *(unsigned*)(&hbuf8[0][r][c]) =
        (unsigned)b4[0] | ((unsigned)b4[1] << 8) | ((unsigned)b4[2] << 16) | ((unsigned)b4[3] << 24);
  }
  for (int i = tid; i < 2 * 16 * 40; i += 1024) (&hp8[0][0][0])[i] = 0;

  // ---- decode-crew state (waves 8..15) ----
  const int wd = w - 8;
  float cst[2][4];
  float rbv[2][4];
  const u8 *wbi[2], *wbf[2];
  if (w >= 8) {
#pragma unroll
    for (int sub = 0; sub < 2; sub++) {
      int g16 = wd * 2 + sub;
#pragma unroll
      for (int r = 0; r < 4; r++)
        cst[sub][r] = C0[(size_t)(rowg + q * 4 + r) * 256 + g16 * 16 + m15];
#pragma unroll
      for (int g = 0; g < 4; g++)
        rbv[sub][g] = rb[g16 * 64 + g * 16 + m15];
      wbi[sub] = Wc8 + (size_t)(g16 * 64 + m15) * 256 + q * 8;          // gate i
      wbf[sub] = Wc8 + (size_t)(g16 * 64 + 16 + m15) * 256 + q * 8;     // gate f
    }
  }

  // ---- pred-crew state (waves 0..7) ----
  const int hloc = lane >> 4, prow = lane & 15;
  const int pcol = w * 4 + hloc;
  const int pc = (w < 8) ? pcol : 0;
  const float pb0 = pb[pc * 4 + 0], pb1 = pb[pc * 4 + 1];
  const float pb2 = pb[pc * 4 + 2], pb3 = pb[pc * 4 + 3];
  f8frag WP8[8], WPH8;
  if (w < 8) {
#pragma unroll
    for (int kt = 0; kt < 8; kt++)
      WP8[kt] = *(const f8frag*)(pW8 + (size_t)(w * 16 + m15) * 256 + kt * 32 + q * 8);
    WPH8 = *(const f8frag*)(pWhh8 + (size_t)(w * 16 + m15) * 32 + q * 8);
  }
  float cp = 0.f;
  __syncthreads();

  for (int s = 0; s < 128; s++) {
    if (w >= 8) {
      // ================= DECODE CREW: step s+1 =================
      if (s < 127) {
        const u8* h8 = &hbuf8[s & 1][0][0];
        f32x4 acc[2][4] = {};
#pragma unroll
        for (int kt = 0; kt < 8; kt++) {
          f8frag a8 = *(const f8frag*)(h8 + m15 * 272 + kt * 32 + q * 8);
#pragma unroll
          for (int sub = 0; sub < 2; sub++) {
            int g16 = wd * 2 + sub;
            f8frag bi = *(const f8frag*)(wbi[sub] + kt * 32);
            f8frag bf = *(const f8frag*)(wbf[sub] + kt * 32);
            f8frag bg = *(const f8frag*)(&wgl8[g16][kt][0] + lane * 8);
            f8frag bo = *(const f8frag*)(&wol8[g16][kt][0] + lane * 8);
            acc[sub][0] = MFMA8(a8, bi, acc[sub][0]);
            acc[sub][1] = MFMA8(a8, bf, acc[sub][1]);
            acc[sub][2] = MFMA8(a8, bg, acc[sub][2]);
            acc[sub][3] = MFMA8(a8, bo, acc[sub][3]);
          }
        }
        u8* hw8 = &hbuf8[(s + 1) & 1][0][0];
#pragma unroll
        for (int sub = 0; sub < 2; sub++) {
          int hc = (wd * 2 + sub) * 16 + m15;
#pragma unroll
          for (int r = 0; r < 4; r++) {
            float gi = acc[sub][0][r] + rbv[sub][0];
            float gf = acc[sub][1][r] + rbv[sub][1];
            float gg = acc[sub][2][r] + rbv[sub][2];
            float go = acc[sub][3][r] + rbv[sub][3];
            float cn = ssig(gf) * cst[sub][r] + ssig(gi) * stanh(gg);
            float hn = ssig(go) * stanh(cn);
            cst[sub][r] = cn;
            hw8[(q * 4 + r) * 272 + hc] = f2e4m3(hn);
          }
        }
      }
    } else {
      // ================= PRED CREW =================
      // phase A: softmax stats + out for step s-1 (register-only, width-32)
      if (s > 0) {
        int row_ = tid >> 5, j = tid & 31;
        float yv = ys[(s - 1) & 1][row_][j];
        float m = (j < 31) ? yv : -1e30f;
#pragma unroll
        for (int off = 16; off; off >>= 1) m = fmaxf(m, __shfl_xor(m, off, 32));
        float es = (j < 31) ? __expf(yv - m) : 0.f;
        float tot = es;
#pragma unroll
        for (int off = 16; off; off >>= 1) tot += __shfl_xor(tot, off, 32);
        float outv = (j < 31) ? es / tot : ssig(yv);
        out[(size_t)(rowg + row_) * 4096 + (s - 1) * 32 + j] = outv;
      }
      // phase B: pred MFMAs for step s (x = h_s, fp8)
      {
        const u8* xr8 = &hbuf8[s & 1][0][0];
        f32x4 pacc = {};
#pragma unroll
        for (int kt = 0; kt < 8; kt++) {
          f8frag a8 = *(const f8frag*)(xr8 + m15 * 272 + kt * 32 + q * 8);
          pacc = MFMA8(a8, WP8[kt], pacc);
        }
        {
          f8frag ah8 = *(const f8frag*)(&hp8[s & 1][m15][q * 8]);
          pacc = MFMA8(ah8, WPH8, pacc);
        }
        *(f32x4*)&gbuf[w][m15][q * 4] = pacc;  // per-wave transpose, in-order DS
        float g0 = gbuf[w][hloc * 4 + 0][prow] + pb0;
        float g1 = gbuf[w][hloc * 4 + 1][prow] + pb1;
        float g2 = gbuf[w][hloc * 4 + 2][prow] + pb2;
        float g3 = gbuf[w][hloc * 4 + 3][prow] + pb3;
        float cn = ssig(g1) * cp + ssig(g0) * stanh(g2);
        float hn_p = ssig(g3) * stanh(cn);
        cp = cn;
        hp8[(s + 1) & 1][prow][pcol] = f2e4m3(hn_p);
        ys[s & 1][prow][pcol] = hn_p;
      }
    }
    __syncthreads();   // single barrier per step
  }
  // final: stats + out for s = 127
  if (tid < 512) {
    int row_ = tid >> 5, j = tid & 31;
    float yv = ys[1][row_][j];   // 127 & 1
    float m = (j < 31) ? yv : -1e30f;
#pragma unroll
    for (int off = 16; off; off >>= 1) m = fmaxf(m, __shfl_xor(m, off, 32));
    float es = (j < 31) ? __expf(yv - m) : 0.f;
    float tot = es;
#pragma unroll
    for (int off = 16; off; off >>= 1) tot += __shfl_xor(tot, off, 32);
    float outv = (j < 31) ? es / tot : ssig(yv);
    out[(size_t)(rowg + row_) * 4096 + 127 * 32 + j] = outv;
  }
}

// ---------------------------------------------------------------------------
extern "C" void kernel_launch(void* const* d_in, const int* in_sizes, int n_in,
                              void* d_out, int out_size, void* d_ws, size_t ws_size,
                              hipStream_t stream) {
  (void)in_sizes; (void)n_in; (void)out_size; (void)ws_size;
  const float* x    = (const float*)d_in[0];
  const float* W1   = (const float*)d_in[1];
  const float* b1   = (const float*)d_in[2];
  const float* W2   = (const float*)d_in[3];
  const float* b2   = (const float*)d_in[4];
  const float* W3   = (const float*)d_in[5];
  const float* b3   = (const float*)d_in[6];
  const float* Wh1  = (const float*)d_in[7];
  const float* bh1  = (const float*)d_in[8];
  const float* Wh2  = (const float*)d_in[9];
  const float* bh2  = (const float*)d_in[10];
  const float* Wc1  = (const float*)d_in[11];
  const float* bc1  = (const float*)d_in[12];
  const float* Wc2  = (const float*)d_in[13];
  const float* bc2  = (const float*)d_in[14];
  const float* Wx1  = (const float*)d_in[15];
  const float* bx1  = (const float*)d_in[16];
  const float* Wx2  = (const float*)d_in[17];
  const float* bx2  = (const float*)d_in[18];
  const float* rWih = (const float*)d_in[19];
  const float* rWhh = (const float*)d_in[20];
  const float* rbih = (const float*)d_in[21];
  const float* rbhh = (const float*)d_in[22];
  const float* pWih = (const float*)d_in[23];
  const float* pWhh = (const float*)d_in[24];
  const float* pbih = (const float*)d_in[25];
  const float* pbhh = (const float*)d_in[26];

  char* w = (char*)d_ws;
  auto alloc = [&](size_t bytes) -> char* {
    char* p = w;
    w += (bytes + 255) & ~(size_t)255;
    return p;
  };
  u16* Xbf  = (u16*)alloc(1024 * 128 * 2);
  u16* T1   = (u16*)alloc(1024 * 512 * 2);
  u16* T2   = (u16*)alloc(1024 * 512 * 2);
  u16* T3   = (u16*)alloc(1024 * 512 * 2);
  u16* TH   = (u16*)alloc(1024 * 512 * 2);
  u16* TC   = (u16*)alloc(1024 * 512 * 2);
  u16* TX   = (u16*)alloc(1024 * 512 * 2);
  u16* X0H  = (u16*)alloc(1024 * 512 * 2);  // cols 0..255 = x0, 256..511 = h
  float* CB = (float*)alloc(1024 * 256 * 4);
  u16* OUTS0= (u16*)alloc(1024 * 256 * 2);  // h_0 only
  u16* W1b  = (u16*)alloc(512 * 128 * 2);
  u16* W2b  = (u16*)alloc(512 * 512 * 2);
  u16* W3b  = (u16*)alloc(512 * 512 * 2);
  u16* Wh1b = (u16*)alloc(512 * 512 * 2);
  u16* Wc1b = (u16*)alloc(512 * 512 * 2);
  u16* Wx1b = (u16*)alloc(512 * 512 * 2);
  u16* Wh2b = (u16*)alloc(256 * 512 * 2);
  u16* Wc2b = (u16*)alloc(256 * 512 * 2);
  u16* Wx2b = (u16*)alloc(256 * 512 * 2);
  u16* WcatR= (u16*)alloc(1024 * 512 * 2);
  u8*  Wc8  = (u8*)alloc(1024 * 256);
  u8*  Wg8  = (u8*)alloc(65536);
  u8*  Wo8  = (u8*)alloc(65536);
  u8*  pW8  = (u8*)alloc(32768);
  u8*  pWhh8= (u8*)alloc(4096);
  float* rbR = (float*)alloc(1024 * 4);
  float* pbR = (float*)alloc(128 * 4);

  PrepArgs pa;
  pa.x = x; pa.W1 = W1; pa.W2 = W2; pa.W3 = W3; pa.Wh1 = Wh1; pa.Wc1 = Wc1; pa.Wx1 = Wx1;
  pa.Wh2 = Wh2; pa.Wc2 = Wc2; pa.Wx2 = Wx2;
  pa.rWih = rWih; pa.rWhh = rWhh; pa.rbih = rbih; pa.rbhh = rbhh;
  pa.pWih = pWih; pa.pWhh = pWhh; pa.pbih = pbih; pa.pbhh = pbhh;
  pa.Xbf = Xbf; pa.W1b = W1b; pa.W2b = W2b; pa.W3b = W3b; pa.Wh1b = Wh1b;
  pa.Wc1b = Wc1b; pa.Wx1b = Wx1b; pa.Wh2b = Wh2b; pa.Wc2b = Wc2b; pa.Wx2b = Wx2b;
  pa.WcatR = WcatR;
  pa.Wc8 = Wc8; pa.Wg8 = Wg8; pa.Wo8 = Wo8; pa.pW8 = pW8; pa.pWhh8 = pWhh8;
  pa.rbR = rbR; pa.pbR = pbR;
  prep<<<dim3(32, 18), 256, 0, stream>>>(pa);

  // MLP + heads
  gemm_act<<<dim3(16, 8), 256, 0, stream>>>(Xbf, W1b, b1, T1, nullptr, 128, 512, 0, 1);
  gemm_act<<<dim3(16, 8), 256, 0, stream>>>(T1, W2b, b2, T2, nullptr, 512, 512, 0, 1);
  gemm_act<<<dim3(16, 8), 256, 0, stream>>>(T2, W3b, b3, T3, nullptr, 512, 512, 0, 1);
  gemm_act<<<dim3(16, 8), 256, 0, stream>>>(T3, Wh1b, bh1, TH, nullptr, 512, 512, 0, 1);
  gemm_act<<<dim3(16, 8), 256, 0, stream>>>(T3, Wc1b, bc1, TC, nullptr, 512, 512, 0, 1);
  gemm_act<<<dim3(16, 8), 256, 0, stream>>>(T3, Wx1b, bx1, TX, nullptr, 512, 512, 0, 1);
  gemm_act<<<dim3(16, 4), 256, 0, stream>>>(TH, Wh2b, bh2, X0H, nullptr, 512, 512, 256, 0); // h
  gemm_act<<<dim3(16, 4), 256, 0, stream>>>(TC, Wc2b, bc2, nullptr, CB, 512, 256, 0, 0);    // c (fp32)
  gemm_act<<<dim3(16, 4), 256, 0, stream>>>(TX, Wx2b, bx2, X0H, nullptr, 512, 512, 0, 0);   // x0

  // decode step 0 (K=512 concat, bf16), then wave-specialized fp8 decode+pred
  decode_step<<<dim3(16, 8), 256, 0, stream>>>(X0H, WcatR, rbR, CB, OUTS0, 512);
  decode_pred<<<64, 1024, 0, stream>>>(Wc8, Wg8, Wo8, rbR, CB, OUTS0,
                                       pW8, pWhh8, pbR, (float*)d_out);
}

// Round 11
// 768.383 us; speedup vs baseline: 1.9668x; 1.9668x over previous
//
#include <hip/hip_runtime.h>
#include <hip/hip_fp8.h>

typedef unsigned short u16;
typedef unsigned char u8;
typedef __attribute__((ext_vector_type(8))) __bf16 bfrag;
typedef long long f8frag;
typedef __attribute__((ext_vector_type(4))) float f32x4;

static __device__ __forceinline__ f32x4 MFMA(bfrag a, bfrag b, f32x4 c) {
  return __builtin_amdgcn_mfma_f32_16x16x32_bf16(a, b, c, 0, 0, 0);
}
static __device__ __forceinline__ f32x4 MFMA8(f8frag a, f8frag b, f32x4 c) {
  return __builtin_amdgcn_mfma_f32_16x16x32_fp8_fp8(a, b, c, 0, 0, 0);
}

// float -> bf16 (RNE)
static __device__ __forceinline__ u16 f2b(float f) {
  union { float f; unsigned u; } v; v.f = f;
  unsigned r = (v.u + 0x7fffu + ((v.u >> 16) & 1u)) >> 16;
  return (u16)r;
}
// float -> fp8 e4m3 (OCP)
static __device__ __forceinline__ u8 f2e4m3(float f) {
  return __hip_fp8_e4m3(f).__x;
}
static __device__ __forceinline__ float ssig(float x) { return 1.f / (1.f + __expf(-x)); }
static __device__ __forceinline__ float stanh(float x) { return 1.f - 2.f / (__expf(2.f * x) + 1.f); }

// ---------------------------------------------------------------------------
// prep. Decode gate-retile: MFMA col n = g16*64 + gate*16 + m15 <-> source
// row gate*256 + g16*16 + m15.
// Case 15: decode weights fp8 LANE-SWIZZLED CONTIGUOUS stream layout:
//   WsS[(((g16*4+gate)*8+kt)*64+lane)*8+j]
//     = fp8( Wcomb[gate*256 + g16*16 + (lane&15)][kt*32 + (lane>>4)*8 + j] )
// so a wave's load of one (gate,kt) fragment is one contiguous 512 B block
// (base + lane*8) -> single-segment coalesced (old row-major layout touched
// 16 cache lines per load instruction).
// Cases 12/13: predictor weights fp8 in the same swizzled form.
// ---------------------------------------------------------------------------
struct PrepArgs {
  const float *x, *W1, *W2, *W3, *Wh1, *Wc1, *Wx1, *Wh2, *Wc2, *Wx2;
  const float *rWih, *rWhh, *rbih, *rbhh, *pWih, *pWhh, *pbih, *pbhh;
  u16 *Xbf, *W1b, *W2b, *W3b, *Wh1b, *Wc1b, *Wx1b, *Wh2b, *Wc2b, *Wx2b;
  u16 *WcatR;
  u8 *WsS, *pWsS, *pWhhS;
  float *rbR, *pbR;
};

__global__ __launch_bounds__(256) void prep(PrepArgs p) {
  const int tid0 = blockIdx.x * 256 + threadIdx.x;
  const int stride = gridDim.x * 256;
  switch (blockIdx.y) {
    case 0: for (int i = tid0; i < 131072; i += stride) p.Xbf[i] = f2b(p.x[i]); break;
    case 1: for (int i = tid0; i < 65536;  i += stride) p.W1b[i] = f2b(p.W1[i]); break;
    case 2: for (int i = tid0; i < 262144; i += stride) p.W2b[i] = f2b(p.W2[i]); break;
    case 3: for (int i = tid0; i < 262144; i += stride) p.W3b[i] = f2b(p.W3[i]); break;
    case 4: for (int i = tid0; i < 262144; i += stride) p.Wh1b[i] = f2b(p.Wh1[i]); break;
    case 5: for (int i = tid0; i < 262144; i += stride) p.Wc1b[i] = f2b(p.Wc1[i]); break;
    case 6: for (int i = tid0; i < 262144; i += stride) p.Wx1b[i] = f2b(p.Wx1[i]); break;
    case 7: for (int i = tid0; i < 131072; i += stride) p.Wh2b[i] = f2b(p.Wh2[i]); break;
    case 8: for (int i = tid0; i < 131072; i += stride) p.Wc2b[i] = f2b(p.Wc2[i]); break;
    case 9: for (int i = tid0; i < 131072; i += stride) p.Wx2b[i] = f2b(p.Wx2[i]); break;
    case 10: // step-0 concat weights (bf16, gate-retiled)
      for (int i = tid0; i < 262144; i += stride) {
        int n = i >> 8, k = i & 255;
        int srow = (((n >> 4) & 3) << 8) + ((n >> 6) << 4) + (n & 15);
        p.WcatR[n * 512 + k] = f2b(p.rWih[srow * 256 + k]);
        p.WcatR[n * 512 + 256 + k] = f2b(p.rWhh[srow * 256 + k]);
      }
      break;
    case 11:
      for (int i = tid0; i < 1024; i += stride) {
        int srow = (((i >> 4) & 3) << 8) + ((i >> 6) << 4) + (i & 15);
        p.rbR[i] = p.rbih[srow] + p.rbhh[srow];
      }
      break;
    case 12: // pred x-weights fp8, swizzled-contiguous
      for (int i = tid0; i < 32768; i += stride) {
        int j = i & 7, lane = (i >> 3) & 63, kt = (i >> 9) & 7, w = i >> 12;
        int n = w * 16 + (lane & 15);
        int srow = ((n & 3) << 5) + (n >> 2);
        int k = kt * 32 + ((lane >> 4) & 3) * 8 + j;
        p.pWsS[i] = f2e4m3(p.pWih[srow * 256 + k]);
      }
      break;
    case 13: // pred h-weights fp8, swizzled-contiguous
      for (int i = tid0; i < 4096; i += stride) {
        int j = i & 7, lane = (i >> 3) & 63, w = i >> 9;
        int n = w * 16 + (lane & 15);
        int srow = ((n & 3) << 5) + (n >> 2);
        int k = ((lane >> 4) & 3) * 8 + j;
        p.pWhhS[i] = f2e4m3(p.pWhh[srow * 32 + k]);
      }
      break;
    case 14:
      for (int i = tid0; i < 128; i += stride) {
        int srow = ((i & 3) << 5) + (i >> 2);
        p.pbR[i] = p.pbih[srow] + p.pbhh[srow];
      }
      break;
    case 15: // decode combined weights fp8, swizzled-contiguous stream layout
      for (int i = tid0; i < 262144; i += stride) {
        int j = i & 7, lane = (i >> 3) & 63, kt = (i >> 9) & 7;
        int gate = (i >> 12) & 3, g16 = i >> 14;
        int srow = gate * 256 + g16 * 16 + (lane & 15);
        int k = kt * 32 + ((lane >> 4) & 3) * 8 + j;
        p.WsS[i] = f2e4m3(p.rWih[srow * 256 + k] + p.rWhh[srow * 256 + k]);
      }
      break;
  }
}

// ---------------------------------------------------------------------------
// gemm_act: Y[1024,N] = act(X[1024,K] @ W[N,K]^T + bias), bf16 in, fp32 acc.
// ---------------------------------------------------------------------------
__global__ __launch_bounds__(256) void gemm_act(
    const u16* __restrict__ X, const u16* __restrict__ W,
    const float* __restrict__ bias,
    u16* __restrict__ Yb, float* __restrict__ Yf,
    int K, int ldo, int coloff, int leaky) {
  const int rt = blockIdx.x, ct = blockIdx.y;
  const int lane = threadIdx.x & 63, wave = threadIdx.x >> 6;
  const int m15 = lane & 15, q = lane >> 4, kq = q * 8;
  const int row = rt * 64 + wave * 16 + m15;
  f32x4 acc[4] = {};
  const u16* xp = X + (size_t)row * K + kq;
  for (int k0 = 0; k0 < K; k0 += 32) {
    bfrag a = *(const bfrag*)(xp + k0);
#pragma unroll
    for (int nt = 0; nt < 4; nt++) {
      const u16* wp = W + (size_t)(ct * 64 + nt * 16 + m15) * K + k0 + kq;
      acc[nt] = MFMA(a, *(const bfrag*)wp, acc[nt]);
    }
  }
#pragma unroll
  for (int nt = 0; nt < 4; nt++) {
    int col = ct * 64 + nt * 16 + m15;
    float bv = bias[col];
#pragma unroll
    for (int r = 0; r < 4; r++) {
      int orow = rt * 64 + wave * 16 + q * 4 + r;
      float v = acc[nt][r] + bv;
      if (leaky) v = v >= 0.f ? v : 0.2f * v;
      if (Yb) Yb[(size_t)orow * ldo + coloff + col] = f2b(v);
      else    Yf[(size_t)orow * ldo + coloff + col] = v;
    }
  }
}

// ---------------------------------------------------------------------------
// decode_step: step 0 only (K=512 concat input, bf16), gate-retiled columns.
// ---------------------------------------------------------------------------
__global__ __launch_bounds__(256) void decode_step(
    const u16* __restrict__ A, const u16* __restrict__ W,
    const float* __restrict__ rb,
    float* __restrict__ C, u16* __restrict__ Hout, int K) {
  __shared__ float g[64][128];
  const int rt = blockIdx.x, cg = blockIdx.y;
  const int lane = threadIdx.x & 63, wave = threadIdx.x >> 6;
  const int m15 = lane & 15, q = lane >> 4, kq = q * 8;
  const int row = rt * 64 + wave * 16 + m15;
  f32x4 acc[8] = {};
  const u16* ap = A + (size_t)row * K + kq;
  for (int k0 = 0; k0 < K; k0 += 32) {
    bfrag a = *(const bfrag*)(ap + k0);
#pragma unroll
    for (int nt = 0; nt < 8; nt++) {
      const u16* wp = W + (size_t)(cg * 128 + nt * 16 + m15) * K + k0 + kq;
      acc[nt] = MFMA(a, *(const bfrag*)wp, acc[nt]);
    }
  }
#pragma unroll
  for (int nt = 0; nt < 8; nt++)
#pragma unroll
    for (int r = 0; r < 4; r++)
      g[wave * 16 + q * 4 + r][nt * 16 + m15] = acc[nt][r];
  __syncthreads();
  for (int t = threadIdx.x; t < 2048; t += 256) {
    int rl = t >> 5, hc = t & 31;
    int grow = rt * 64 + rl, gcol = cg * 32 + hc;
    int base = ((hc >> 4) << 6) + (hc & 15);
    float gi = g[rl][base +  0] + rb[cg * 128 + base +  0];
    float gf = g[rl][base + 16] + rb[cg * 128 + base + 16];
    float gg = g[rl][base + 32] + rb[cg * 128 + base + 32];
    float go = g[rl][base + 48] + rb[cg * 128 + base + 48];
    size_t ci = (size_t)grow * 256 + gcol;
    float c = C[ci];
    float cn = ssig(gf) * c + ssig(gi) * stanh(gg);
    float hn = ssig(go) * stanh(cn);
    C[ci] = cn;
    Hout[ci] = f2b(hn);
  }
}

// ---------------------------------------------------------------------------
// decode_pred v6 (batched-prefetch): 64 blocks x 1024 thr, 16 rows/block,
// wave w = all 4 gates of hcols w*16..+15 (in-lane LSTM), fused fp8 pred.
// R3-R10 diagnosis: ~70% of each step is all-wave stall; streamed B-frag
// loads were 16-segment scattered AND serialized by the 64-VGPR budget
// (one L2 round-trip per load). Fix: (1) swizzled-contiguous weight layout
// (one 512 B block per fragment, addr = base + lane*8); (2) explicit batch
// prefetch of all 32 weight frags + 8 A-frags into registers before the
// MFMA burst (~114 VGPRs live; launch_bounds(1024,4) allows 128; only 64
// blocks exist so >64 VGPR costs no occupancy). One L2 latency per step.
// ONE barrier per step (phase1 decode-write -> barrier -> phase2 pred).
// ---------------------------------------------------------------------------
__global__ __launch_bounds__(1024, 4) void decode_pred(
    const u8* __restrict__ WsS,     // [262144] swizzled fp8 decode weights
    const float* __restrict__ rb,   // rbR [1024]
    const float* __restrict__ C0,   // CB  [1024][256] (c after step 0)
    const u16* __restrict__ H0,     // h_0 [1024][256] bf16
    const u8* __restrict__ pWsS,    // [32768] swizzled fp8 pred x-weights
    const u8* __restrict__ pWhhS,   // [4096] swizzled fp8 pred h-weights
    const float* __restrict__ pb,   // pbR [128]
    float* __restrict__ out) {      // [1024][128][32]
  __shared__ u8 hbuf8[2][16][272];     // 8.5 KB fp8 h ping-pong
  __shared__ float gbuf[8][16][20];    // 10 KB pred transpose
  __shared__ u8 hp8[2][16][40];        // 1.25 KB pred hidden
  __shared__ float ys[2][16][36];      // 4.5 KB pred y double-buffer
  const int tid = threadIdx.x;
  const int w = tid >> 6, lane = tid & 63;
  const int m15 = lane & 15, q = lane >> 4;
  const int rowg = blockIdx.x * 16;
  const int hc = w * 16 + m15;

  // h_0 -> fp8
  {
    int r = tid >> 6, c = (tid & 63) * 4;
    const u16* src = H0 + (size_t)(rowg + r) * 256 + c;
    u8 b4[4];
#pragma unroll
    for (int j = 0; j < 4; j++) {
      union { float f; unsigned u; } v; v.u = (unsigned)src[j] << 16;
      b4[j] = f2e4m3(v.f);
    }
    *(unsigned*)(&hbuf8[0][r][c]) =
        (unsigned)b4[0] | ((unsigned)b4[1] << 8) | ((unsigned)b4[2] << 16) | ((unsigned)b4[3] << 24);
  }
  for (int i = tid; i < 2 * 16 * 40; i += 1024) (&hp8[0][0][0])[i] = 0;

  // decode per-lane state
  float cst[4];
#pragma unroll
  for (int r = 0; r < 4; r++)
    cst[r] = C0[(size_t)(rowg + q * 4 + r) * 256 + hc];
  const float rbv0 = rb[w * 64 +  0 + m15], rbv1 = rb[w * 64 + 16 + m15];
  const float rbv2 = rb[w * 64 + 32 + m15], rbv3 = rb[w * 64 + 48 + m15];
  const u8* wsb = WsS + (size_t)w * 16384 + lane * 8;   // wave's swizzled base

  // pred constants (waves 0..7)
  const int hloc = lane >> 4, prow = lane & 15;
  const int pcol = w * 4 + hloc;
  const int pc = (w < 8) ? pcol : 0;
  const float pb0 = pb[pc * 4 + 0], pb1 = pb[pc * 4 + 1];
  const float pb2 = pb[pc * 4 + 2], pb3 = pb[pc * 4 + 3];
  const u8* pwsb = pWsS + (size_t)(w & 7) * 4096 + lane * 8;
  const u8* pwhb = pWhhS + (size_t)(w & 7) * 512 + lane * 8;
  float cp = 0.f;
  __syncthreads();

  for (int s = 0; s < 128; s++) {
    // ---------- phase 1: decode step s (all 16 waves) ----------
    if (s) {
      const u8* h8 = &hbuf8[(s - 1) & 1][0][0];
      // batch-prefetch ALL weight fragments (contiguous 512B each, one
      // latency for the whole batch), then A-frags from LDS
      f8frag Wv0[8], Wv1[8], Wv2[8], Wv3[8];
#pragma unroll
      for (int kt = 0; kt < 8; kt++) {
        Wv0[kt] = *(const f8frag*)(wsb + kt * 512);            // gate i
        Wv1[kt] = *(const f8frag*)(wsb + 4096 + kt * 512);     // gate f
        Wv2[kt] = *(const f8frag*)(wsb + 8192 + kt * 512);     // gate g
        Wv3[kt] = *(const f8frag*)(wsb + 12288 + kt * 512);    // gate o
      }
      f8frag a8v[8];
#pragma unroll
      for (int kt = 0; kt < 8; kt++)
        a8v[kt] = *(const f8frag*)(h8 + m15 * 272 + kt * 32 + q * 8);
      f32x4 ai = {}, af_ = {}, ag = {}, ao = {};
#pragma unroll
      for (int kt = 0; kt < 8; kt++) {
        ai  = MFMA8(a8v[kt], Wv0[kt], ai);
        af_ = MFMA8(a8v[kt], Wv1[kt], af_);
        ag  = MFMA8(a8v[kt], Wv2[kt], ag);
        ao  = MFMA8(a8v[kt], Wv3[kt], ao);
      }
      u8* hw8 = &hbuf8[s & 1][0][0];
#pragma unroll
      for (int r = 0; r < 4; r++) {
        float gi = ai[r] + rbv0, gf = af_[r] + rbv1;
        float gg = ag[r] + rbv2, go = ao[r] + rbv3;
        float cn = ssig(gf) * cst[r] + ssig(gi) * stanh(gg);
        float hn = ssig(go) * stanh(cn);
        cst[r] = cn;
        hw8[(q * 4 + r) * 272 + hc] = f2e4m3(hn);
      }
    }
    __syncthreads();   // h_s complete; also orders last iter's pred writes
    // ---------- phase 2: pred step s + softmax/out for s-1 (waves 0..7) ----
    if (w < 8) {
      if (s > 0) {   // register-shuffle softmax over ys[s-1]
        int row_ = tid >> 5, j = tid & 31;
        float yv = ys[(s - 1) & 1][row_][j];
        float m = (j < 31) ? yv : -1e30f;
#pragma unroll
        for (int off = 16; off; off >>= 1) m = fmaxf(m, __shfl_xor(m, off, 32));
        float es = (j < 31) ? __expf(yv - m) : 0.f;
        float tot = es;
#pragma unroll
        for (int off = 16; off; off >>= 1) tot += __shfl_xor(tot, off, 32);
        float outv = (j < 31) ? es / tot : ssig(yv);
        out[(size_t)(rowg + row_) * 4096 + (s - 1) * 32 + j] = outv;
      }
      {
        const u8* xr8 = &hbuf8[s & 1][0][0];
        f8frag pbv[8], pav[8];
#pragma unroll
        for (int kt = 0; kt < 8; kt++) pbv[kt] = *(const f8frag*)(pwsb + kt * 512);
        f8frag phw = *(const f8frag*)pwhb;
#pragma unroll
        for (int kt = 0; kt < 8; kt++)
          pav[kt] = *(const f8frag*)(xr8 + m15 * 272 + kt * 32 + q * 8);
        f8frag pah = *(const f8frag*)(&hp8[s & 1][m15][q * 8]);
        f32x4 pacc = {};
#pragma unroll
        for (int kt = 0; kt < 8; kt++) pacc = MFMA8(pav[kt], pbv[kt], pacc);
        pacc = MFMA8(pah, phw, pacc);
        *(f32x4*)&gbuf[w][m15][q * 4] = pacc;  // per-wave transpose, in-order DS
        float g0 = gbuf[w][hloc * 4 + 0][prow] + pb0;
        float g1 = gbuf[w][hloc * 4 + 1][prow] + pb1;
        float g2 = gbuf[w][hloc * 4 + 2][prow] + pb2;
        float g3 = gbuf[w][hloc * 4 + 3][prow] + pb3;
        float cn = ssig(g1) * cp + ssig(g0) * stanh(g2);
        float hn_p = ssig(g3) * stanh(cn);
        cp = cn;
        hp8[(s + 1) & 1][prow][pcol] = f2e4m3(hn_p);
        ys[s & 1][prow][pcol] = hn_p;
      }
    }
  }
  __syncthreads();
  // epilogue: softmax + out for s = 127
  if (tid < 512) {
    int row_ = tid >> 5, j = tid & 31;
    float yv = ys[1][row_][j];
    float m = (j < 31) ? yv : -1e30f;
#pragma unroll
    for (int off = 16; off; off >>= 1) m = fmaxf(m, __shfl_xor(m, off, 32));
    float es = (j < 31) ? __expf(yv - m) : 0.f;
    float tot = es;
#pragma unroll
    for (int off = 16; off; off >>= 1) tot += __shfl_xor(tot, off, 32);
    float outv = (j < 31) ? es / tot : ssig(yv);
    out[(size_t)(rowg + row_) * 4096 + 127 * 32 + j] = outv;
  }
}

// ---------------------------------------------------------------------------
extern "C" void kernel_launch(void* const* d_in, const int* in_sizes, int n_in,
                              void* d_out, int out_size, void* d_ws, size_t ws_size,
                              hipStream_t stream) {
  (void)in_sizes; (void)n_in; (void)out_size; (void)ws_size;
  const float* x    = (const float*)d_in[0];
  const float* W1   = (const float*)d_in[1];
  const float* b1   = (const float*)d_in[2];
  const float* W2   = (const float*)d_in[3];
  const float* b2   = (const float*)d_in[4];
  const float* W3   = (const float*)d_in[5];
  const float* b3   = (const float*)d_in[6];
  const float* Wh1  = (const float*)d_in[7];
  const float* bh1  = (const float*)d_in[8];
  const float* Wh2  = (const float*)d_in[9];
  const float* bh2  = (const float*)d_in[10];
  const float* Wc1  = (const float*)d_in[11];
  const float* bc1  = (const float*)d_in[12];
  const float* Wc2  = (const float*)d_in[13];
  const float* bc2  = (const float*)d_in[14];
  const float* Wx1  = (const float*)d_in[15];
  const float* bx1  = (const float*)d_in[16];
  const float* Wx2  = (const float*)d_in[17];
  const float* bx2  = (const float*)d_in[18];
  const float* rWih = (const float*)d_in[19];
  const float* rWhh = (const float*)d_in[20];
  const float* rbih = (const float*)d_in[21];
  const float* rbhh = (const float*)d_in[22];
  const float* pWih = (const float*)d_in[23];
  const float* pWhh = (const float*)d_in[24];
  const float* pbih = (const float*)d_in[25];
  const float* pbhh = (const float*)d_in[26];

  char* w = (char*)d_ws;
  auto alloc = [&](size_t bytes) -> char* {
    char* p = w;
    w += (bytes + 255) & ~(size_t)255;
    return p;
  };
  u16* Xbf  = (u16*)alloc(1024 * 128 * 2);
  u16* T1   = (u16*)alloc(1024 * 512 * 2);
  u16* T2   = (u16*)alloc(1024 * 512 * 2);
  u16* T3   = (u16*)alloc(1024 * 512 * 2);
  u16* TH   = (u16*)alloc(1024 * 512 * 2);
  u16* TC   = (u16*)alloc(1024 * 512 * 2);
  u16* TX   = (u16*)alloc(1024 * 512 * 2);
  u16* X0H  = (u16*)alloc(1024 * 512 * 2);  // cols 0..255 = x0, 256..511 = h
  float* CB = (float*)alloc(1024 * 256 * 4);
  u16* OUTS0= (u16*)alloc(1024 * 256 * 2);  // h_0 only
  u16* W1b  = (u16*)alloc(512 * 128 * 2);
  u16* W2b  = (u16*)alloc(512 * 512 * 2);
  u16* W3b  = (u16*)alloc(512 * 512 * 2);
  u16* Wh1b = (u16*)alloc(512 * 512 * 2);
  u16* Wc1b = (u16*)alloc(512 * 512 * 2);
  u16* Wx1b = (u16*)alloc(512 * 512 * 2);
  u16* Wh2b = (u16*)alloc(256 * 512 * 2);
  u16* Wc2b = (u16*)alloc(256 * 512 * 2);
  u16* Wx2b = (u16*)alloc(256 * 512 * 2);
  u16* WcatR= (u16*)alloc(1024 * 512 * 2);
  u8*  WsS  = (u8*)alloc(262144);
  u8*  pWsS = (u8*)alloc(32768);
  u8*  pWhhS= (u8*)alloc(4096);
  float* rbR = (float*)alloc(1024 * 4);
  float* pbR = (float*)alloc(128 * 4);

  PrepArgs pa;
  pa.x = x; pa.W1 = W1; pa.W2 = W2; pa.W3 = W3; pa.Wh1 = Wh1; pa.Wc1 = Wc1; pa.Wx1 = Wx1;
  pa.Wh2 = Wh2; pa.Wc2 = Wc2; pa.Wx2 = Wx2;
  pa.rWih = rWih; pa.rWhh = rWhh; pa.rbih = rbih; pa.rbhh = rbhh;
  pa.pWih = pWih; pa.pWhh = pWhh; pa.pbih = pbih; pa.pbhh = pbhh;
  pa.Xbf = Xbf; pa.W1b = W1b; pa.W2b = W2b; pa.W3b = W3b; pa.Wh1b = Wh1b;
  pa.Wc1b = Wc1b; pa.Wx1b = Wx1b; pa.Wh2b = Wh2b; pa.Wc2b = Wc2b; pa.Wx2b = Wx2b;
  pa.WcatR = WcatR;
  pa.WsS = WsS; pa.pWsS = pWsS; pa.pWhhS = pWhhS;
  pa.rbR = rbR; pa.pbR = pbR;
  prep<<<dim3(32, 16), 256, 0, stream>>>(pa);

  // MLP + heads
  gemm_act<<<dim3(16, 8), 256, 0, stream>>>(Xbf, W1b, b1, T1, nullptr, 128, 512, 0, 1);
  gemm_act<<<dim3(16, 8), 256, 0, stream>>>(T1, W2b, b2, T2, nullptr, 512, 512, 0, 1);
  gemm_act<<<dim3(16, 8), 256, 0, stream>>>(T2, W3b, b3, T3, nullptr, 512, 512, 0, 1);
  gemm_act<<<dim3(16, 8), 256, 0, stream>>>(T3, Wh1b, bh1, TH, nullptr, 512, 512, 0, 1);
  gemm_act<<<dim3(16, 8), 256, 0, stream>>>(T3, Wc1b, bc1, TC, nullptr, 512, 512, 0, 1);
  gemm_act<<<dim3(16, 8), 256, 0, stream>>>(T3, Wx1b, bx1, TX, nullptr, 512, 512, 0, 1);
  gemm_act<<<dim3(16, 4), 256, 0, stream>>>(TH, Wh2b, bh2, X0H, nullptr, 512, 512, 256, 0); // h
  gemm_act<<<dim3(16, 4), 256, 0, stream>>>(TC, Wc2b, bc2, nullptr, CB, 512, 256, 0, 0);    // c (fp32)
  gemm_act<<<dim3(16, 4), 256, 0, stream>>>(TX, Wx2b, bx2, X0H, nullptr, 512, 512, 0, 0);   // x0

  // decode step 0 (K=512 concat, bf16), then batched-prefetch fp8 decode+pred
  decode_step<<<dim3(16, 8), 256, 0, stream>>>(X0H, WcatR, rbR, CB, OUTS0, 512);
  decode_pred<<<64, 1024, 0, stream>>>(WsS, rbR, CB, OUTS0, pWsS, pWhhS, pbR,
                                       (float*)d_out);
}